// Round 1
// baseline (297.605 us; speedup 1.0000x reference)
//
#include <hip/hip_runtime.h>

typedef short bf16x8 __attribute__((ext_vector_type(8)));
typedef float f32x4 __attribute__((ext_vector_type(4)));

__device__ __forceinline__ unsigned short f2b(float f) {
    unsigned int u = __builtin_bit_cast(unsigned int, f);
    u += 0x7fffu + ((u >> 16) & 1u);   // RNE
    return (unsigned short)(u >> 16);
}
__device__ __forceinline__ float b2f(unsigned short s) {
    unsigned int u = ((unsigned int)s) << 16;
    return __builtin_bit_cast(float, u);
}

// wt[k][i][j] = bf16(w1[j][k][i]);  k<3, i<128, j<64
__global__ void wt_prepass(const float* __restrict__ w1, unsigned short* __restrict__ wt) {
    int t = blockIdx.x * 256 + threadIdx.x;
    if (t >= 24576) return;
    int j = t & 63;
    int i = (t >> 6) & 127;
    int k = t >> 13;
    wt[t] = f2b(w1[(j * 3 + k) * 128 + i]);
}

#define NSLOT 12

// block = (b, bc): computes t4 rows (a, cl) for a in [0,28), cl in [0,8),
//   c(cl) = (7*bc - 1 + cl + 28) % 28   (cyclic; only bc==0 wraps)
// then y[b, i, m, l] for m in [7bc, 7bc+7), all i, all l.
__global__ __launch_bounds__(256, 2) void fused_main(
        const float* __restrict__ x, const float* __restrict__ w0,
        const unsigned short* __restrict__ wt, float* __restrict__ y) {
    // union: phase1/2: xs[28][NSLOT][64] bf16 swizzled (43008 B)
    //        phase3  : t4s[224][73] bf16 (32704 B)
    __shared__ __align__(16) char smem[28 * NSLOT * 64 * 2];
    __shared__ float w0s[256];
    unsigned short* t4s = (unsigned short*)smem;

    const int tid  = threadIdx.x;
    const int lane = tid & 63;
    const int w    = tid >> 6;          // wave 0..3
    const int b    = blockIdx.x >> 2;
    const int bc   = blockIdx.x & 3;
    const int c0   = 7 * bc;
    const int rl   = lane & 15;
    const int jb0  = (lane >> 4) << 3;

    w0s[tid] = w0[tid];  // 256 floats = (128,2)

    // ---- B fragments in registers: bf[p][s], i = w*32 + p*16 + rl ----
    bf16x8 bf[2][6];
#pragma unroll
    for (int s = 0; s < 6; ++s) {
        int k  = s >> 1;
        int jb = ((s & 1) << 5) + jb0;
#pragma unroll
        for (int p = 0; p < 2; ++p) {
            int i = (w << 5) + (p << 4) + rl;
            bf[p][s] = *reinterpret_cast<const bf16x8*>(wt + (k << 13) + (i << 6) + jb);
        }
    }

    // ---- stage x -> xs (transposed to [a][slot][j], bf16, XOR-swizzled) ----
    // slot content n:  bc==0: s<3 -> 26+s (28 -> zero) ; s>=3 -> s-4
    //                  bc>0 : s -> c0-2+s              (outside [0,28) -> zero)
    const size_t xb = (size_t)b * (1792 * 28);
    for (int it = 0; it < 7; ++it) {
        int R = tid + (it << 8);          // x row index, 0..1791 ; R = j*28 + a
        int a = R % 28;
        int j = R / 28;
        const float* xrow = x + xb + (size_t)R * 28;
        int rowbase = a * NSLOT;
#pragma unroll
        for (int s = 0; s < NSLOT; ++s) {
            int n = (bc == 0) ? ((s < 3) ? (26 + s) : (s - 4)) : (c0 - 2 + s);
            float v = ((unsigned)n < 28u) ? xrow[n] : 0.0f;
            int row  = rowbase + s;
            int byte = (row << 7) + ((j << 1) ^ ((row & 7) << 4));
            *(unsigned short*)(smem + byte) = f2b(v);
        }
    }
    __syncthreads();

    // ---- K-loop: per wave 14 m-tiles x 2 n-tiles, 6 K-steps of 32 ----
    f32x4 acc[14][2];
#pragma unroll
    for (int mt = 0; mt < 14; ++mt) { acc[mt][0] = f32x4{0.f,0.f,0.f,0.f}; acc[mt][1] = f32x4{0.f,0.f,0.f,0.f}; }

#pragma unroll
    for (int s = 0; s < 6; ++s) {
        const int k  = s >> 1;
        const int jb = ((s & 1) << 5) + jb0;
#pragma unroll
        for (int mt = 0; mt < 14; ++mt) {
            int r  = (mt << 4) + rl;           // A row = a*8 + cl
            int a  = r >> 3;
            int cl = r & 7;
            int sIdx = (bc == 0) ? ((cl == 0) ? k : (cl + k + 2)) : (cl + k);
            int row  = a * NSLOT + sIdx;
            int byte = (row << 7) + ((jb << 1) ^ ((row & 7) << 4));
            bf16x8 af = *(const bf16x8*)(smem + byte);
            acc[mt][0] = __builtin_amdgcn_mfma_f32_16x16x32_bf16(af, bf[0][s], acc[mt][0], 0, 0, 0);
            acc[mt][1] = __builtin_amdgcn_mfma_f32_16x16x32_bf16(af, bf[1][s], acc[mt][1], 0, 0, 0);
        }
    }
    __syncthreads();

    // ---- epilogue in two i-halves (t4s reuses xs space) ----
#pragma unroll
    for (int h = 0; h < 2; ++h) {
        if ((w >> 1) == h) {
            int icbase = ((w & 1) << 5) + rl;
            int rq = (lane >> 4) << 2;
#pragma unroll
            for (int mt = 0; mt < 14; ++mt) {
#pragma unroll
                for (int p = 0; p < 2; ++p) {
                    int ic = icbase + (p << 4);
#pragma unroll
                    for (int q = 0; q < 4; ++q) {
                        int r = (mt << 4) + rq + q;
                        t4s[r * 73 + ic] = f2b(acc[mt][p][q]);
                    }
                }
            }
        }
        __syncthreads();
        // y[b, i, m, l] for i in this half; coalesced float4 over l
        for (int f = tid; f < 64 * 49; f += 256) {
            int lq    = f % 7;
            int t1    = f / 7;
            int m_loc = t1 % 7;
            int iloc  = t1 / 7;
            int i = (h << 6) + iloc;
            float w00 = w0s[2 * i], w01 = w0s[2 * i + 1];
            int m = c0 + m_loc;
            float4 o;
            float ov[4];
#pragma unroll
            for (int u = 0; u < 4; ++u) {
                int l  = (lq << 2) + u;
                int ap = (l == 0) ? 27 : (l - 1);          // a = (l-1) mod 28
                float v1 = b2f(t4s[(ap * 8 + m_loc + 1) * 73 + iloc]);  // c = m
                float v2 = b2f(t4s[(ap * 8 + m_loc) * 73 + iloc]);      // c = (m-1) mod 28
                ov[u] = w00 * v1 + w01 * v2;
            }
            o.x = ov[0]; o.y = ov[1]; o.z = ov[2]; o.w = ov[3];
            *reinterpret_cast<float4*>(y + ((((size_t)b * 128 + i) * 28 + m) * 28) + (lq << 2)) = o;
        }
        __syncthreads();
    }
}

extern "C" void kernel_launch(void* const* d_in, const int* in_sizes, int n_in,
                              void* d_out, int out_size, void* d_ws, size_t ws_size,
                              hipStream_t stream) {
    const float* x  = (const float*)d_in[0];
    const float* w0 = (const float*)d_in[1];
    const float* w1 = (const float*)d_in[2];
    unsigned short* wt = (unsigned short*)d_ws;   // 24576 u16 = 48 KiB
    float* y = (float*)d_out;

    hipLaunchKernelGGL(wt_prepass, dim3(96), dim3(256), 0, stream, w1, wt);
    hipLaunchKernelGGL(fused_main, dim3(4096), dim3(256), 0, stream, x, w0, wt, y);
}